// Round 1
// 3870.274 us; speedup vs baseline: 1.2935x; 1.2935x over previous
//
#include <hip/hip_runtime.h>
#include <math.h>

#define H 1024
#define BB 64
#define TT 256
#define G3 3072
#define SCAN_BLOCKS 64

typedef __attribute__((ext_vector_type(8))) short bf16x8;
typedef __attribute__((ext_vector_type(4))) float f32x4;

__device__ __forceinline__ unsigned short f2bf(float f) {
    union { float f; unsigned int i; } v; v.f = f;
    unsigned int x = v.i;
    unsigned int r = (x + 0x7fffu + ((x >> 16) & 1u)) >> 16;   // RNE
    return (unsigned short)r;
}
__device__ __forceinline__ float bf2f(unsigned short u) {
    union { unsigned int i; float f; } v; v.i = ((unsigned int)u) << 16; return v.f;
}

// f32 -> bf16 bulk convert (for W_ih / W_hh), 4 elems/thread
__global__ void cvt_f32_bf16(const float* __restrict__ src,
                             unsigned short* __restrict__ dst) {
    int i = (blockIdx.x * 256 + threadIdx.x) * 4;
    float4 v = *(const float4*)(src + i);
    ushort4 o;
    o.x = f2bf(v.x); o.y = f2bf(v.y); o.z = f2bf(v.z); o.w = f2bf(v.w);
    *(ushort4*)(dst + i) = o;
}

// init: hf = h0 (f32), hb = bf16(h0), zero the grid-barrier counter
__global__ void init_all(const float* __restrict__ h0,
                         float* __restrict__ hf, unsigned short* __restrict__ hb,
                         unsigned int* __restrict__ cnt) {
    int i = blockIdx.x * 256 + threadIdx.x;
    if (i == 0) *cnt = 0u;             // kernel boundary orders this vs scan
    float v = h0[i];
    hf[i] = v;
    hb[i] = f2bf(v);
}

// load 8 consecutive f32, relu, convert to bf16x8
__device__ __forceinline__ bf16x8 load8_relu_bf(const float* p) {
    float4 u = *(const float4*)p;
    float4 v = *(const float4*)(p + 4);
    bf16x8 r;
    r[0] = (short)f2bf(fmaxf(u.x, 0.f));
    r[1] = (short)f2bf(fmaxf(u.y, 0.f));
    r[2] = (short)f2bf(fmaxf(u.z, 0.f));
    r[3] = (short)f2bf(fmaxf(u.w, 0.f));
    r[4] = (short)f2bf(fmaxf(v.x, 0.f));
    r[5] = (short)f2bf(fmaxf(v.y, 0.f));
    r[6] = (short)f2bf(fmaxf(v.z, 0.f));
    r[7] = (short)f2bf(fmaxf(v.w, 0.f));
    return r;
}

// ---- xp_chunk = relu(emb[tokens]) @ W_ih^T + b_ih -> bf16 [Tl*64, 3072] ----
// (unchanged from the passing round)
__global__ __launch_bounds__(256) void gemm_xp(
    const float* __restrict__ emb,
    const int* __restrict__ tokens,
    const unsigned short* __restrict__ Wb,
    const float* __restrict__ b_ih,
    unsigned short* __restrict__ xp,
    int row0)
{
    const int tileN = blockIdx.x * 128;
    const int tileM = blockIdx.y * 128;
    const int wave  = threadIdx.x >> 6;
    const int lane  = threadIdx.x & 63;
    const int row   = lane & 15;
    const int quad  = lane >> 4;
    const int mb = tileM + (wave >> 1) * 64;
    const int nb = tileN + (wave & 1) * 64;

    const float* arow[4];
#pragma unroll
    for (int i = 0; i < 4; i++) {
        int tok = tokens[row0 + mb + row + i * 16];
        arow[i] = emb + (size_t)tok * H + quad * 8;
    }
    const unsigned short* bptr = Wb + (size_t)(nb + row) * H + quad * 8;

    f32x4 acc[4][4] = {};
    for (int k = 0; k < H; k += 32) {
        bf16x8 a[4], b[4];
#pragma unroll
        for (int i = 0; i < 4; i++) a[i] = load8_relu_bf(arow[i] + k);
#pragma unroll
        for (int j = 0; j < 4; j++) b[j] = *(const bf16x8*)(bptr + (size_t)j * 16 * H + k);
#pragma unroll
        for (int i = 0; i < 4; i++)
#pragma unroll
            for (int j = 0; j < 4; j++)
                acc[i][j] = __builtin_amdgcn_mfma_f32_16x16x32_bf16(a[i], b[j], acc[i][j], 0, 0, 0);
    }

#pragma unroll
    for (int i = 0; i < 4; i++) {
        int m = mb + i * 16 + quad * 4;
#pragma unroll
        for (int j = 0; j < 4; j++) {
            int n = nb + j * 16 + row;
            float bias = b_ih[n];
#pragma unroll
            for (int rg = 0; rg < 4; rg++) {
                xp[(size_t)(m + rg) * G3 + n] = f2bf(acc[i][j][rg] + bias);
            }
        }
    }
}

// ---- persistent GRU scan: one launch per xp chunk, grid barrier per step ----
// Coherence redesign: the ONLY cross-block data is the h state and the
// barrier counter. Both go through the device coherence point explicitly
// (relaxed agent-scope atomics -> sc1 loads/stores that bypass the
// non-coherent per-XCD L2). NO __threadfence / buffer_wbl2 / buffer_inv
// anywhere in the step loop, so W_hh / xp / biases stay hot in L1+L2 for
// all 256 steps. Release = per-wave s_waitcnt vmcnt(0) (write-through h
// stores are globally visible once acked) + syncthreads + relaxed add.
// Acquire = relaxed poll (bypassing loads never see stale cache lines).
__global__ __launch_bounds__(256) void gru_scan(
    unsigned short* __restrict__ hb0,          // bf16 h ping [64*1024]
    unsigned short* __restrict__ hb1,          // bf16 h pong
    float* __restrict__ hf,                    // f32 h (chunk handoff)
    const unsigned short* __restrict__ Whb,    // [3072,1024] bf16
    const float* __restrict__ b_hh,            // [3072] f32
    const unsigned short* __restrict__ xp,     // chunk base, [Tl*64, 3072] bf16
    float* __restrict__ out,                   // [B,T,H] f32
    unsigned int* __restrict__ cnt,            // grid-barrier counter
    int t0, int Tl)
{
    const int j0   = blockIdx.x * 16;
    const int wave = threadIdx.x >> 6;
    const int lane = threadIdx.x & 63;
    const int row  = lane & 15;
    const int quad = lane >> 4;
    const int m0   = wave * 16;
    const int cj   = j0 + row;

    const float bhr = b_hh[cj];
    const float bhz = b_hh[H + cj];
    const float bhn = b_hh[2 * H + cj];

    const unsigned short* w0 = Whb + (size_t)(0 * H + j0 + row) * H + quad * 8;
    const unsigned short* w1 = Whb + (size_t)(1 * H + j0 + row) * H + quad * 8;
    const unsigned short* w2 = Whb + (size_t)(2 * H + j0 + row) * H + quad * 8;

    float hprev[4];
#pragma unroll
    for (int i = 0; i < 4; i++) hprev[i] = hf[(m0 + quad * 4 + i) * H + cj];

    for (int s = 0; s < Tl; s++) {
        const int t = t0 + s;
        const unsigned short* hin  = (t & 1) ? hb1 : hb0;
        unsigned short*       hout = (t & 1) ? hb0 : hb1;

        // xp loads are independent of h: issue before the GEMM so their
        // latency hides under the MFMA k-loop (normal cached loads; xp is
        // never invalidated now, so these hit L1/L2 after the first touch).
        float xr[4], xz[4], xn[4];
#pragma unroll
        for (int i = 0; i < 4; i++) {
            int b = m0 + quad * 4 + i;
            const unsigned short* xpb = xp + ((size_t)s * BB + b) * G3;
            xr[i] = bf2f(xpb[cj]);
            xz[i] = bf2f(xpb[H + cj]);
            xn[i] = bf2f(xpb[2 * H + cj]);
        }

        f32x4 acc0 = {}, acc1 = {}, acc2 = {};
        // h loads: relaxed agent-scope 8B atomics -> sc1, bypass stale
        // L1/L2, read the coherence point directly. Compiler tracks vmcnt
        // and pipelines them against the MFMA chain.
        const unsigned short* aptr = hin + (size_t)(m0 + row) * H + quad * 8;
        for (int k = 0; k < H; k += 32) {
            union { bf16x8 v; unsigned long long u[2]; } a;
            a.u[0] = __hip_atomic_load((const unsigned long long*)(aptr + k),
                                       __ATOMIC_RELAXED, __HIP_MEMORY_SCOPE_AGENT);
            a.u[1] = __hip_atomic_load((const unsigned long long*)(aptr + k + 4),
                                       __ATOMIC_RELAXED, __HIP_MEMORY_SCOPE_AGENT);
            bf16x8 f0 = *(const bf16x8*)(w0 + k);
            bf16x8 f1 = *(const bf16x8*)(w1 + k);
            bf16x8 f2 = *(const bf16x8*)(w2 + k);
            acc0 = __builtin_amdgcn_mfma_f32_16x16x32_bf16(a.v, f0, acc0, 0, 0, 0);
            acc1 = __builtin_amdgcn_mfma_f32_16x16x32_bf16(a.v, f1, acc1, 0, 0, 0);
            acc2 = __builtin_amdgcn_mfma_f32_16x16x32_bf16(a.v, f2, acc2, 0, 0, 0);
        }

#pragma unroll
        for (int i = 0; i < 4; i++) {
            int b = m0 + quad * 4 + i;
            float hr = acc0[i] + bhr;
            float hz = acc1[i] + bhz;
            float hn = acc2[i] + bhn;
            float r = 1.f / (1.f + __expf(-(xr[i] + hr)));
            float z = 1.f / (1.f + __expf(-(xz[i] + hz)));
            float targ = xn[i] + r * hn;
            targ = fminf(fmaxf(targ, -30.f), 30.f);
            float n = tanhf(targ);
            float hnew = (1.f - z) * n + z * hprev[i];
            hnew = fminf(fmaxf(hnew, -4.f), 4.f);   // invisible when correct
            hprev[i] = hnew;

            // h store: pair adjacent columns (lanes r, r^1) into one 4B
            // write-through agent-scope atomic store -> visible at the
            // coherence point once vmcnt retires.
            unsigned int mybf = (unsigned int)f2bf(hnew);
            unsigned int pbf  = (unsigned int)__shfl_xor((int)mybf, 1);
            if (!(row & 1)) {
                unsigned int word = (mybf & 0xffffu) | (pbf << 16);
                __hip_atomic_store((unsigned int*)(hout + (size_t)b * H + (cj & ~1)),
                                   word, __ATOMIC_RELAXED, __HIP_MEMORY_SCOPE_AGENT);
            }
            out[((size_t)b * TT + t) * H + cj] = hnew;   // normal store; kernel-end flush
        }

        // ---- grid barrier (fence-free) ----
        // Each wave drains its own vmem (h write-through stores acked at the
        // coherence point), then one relaxed add + relaxed poll. No cache
        // writeback/invalidate instructions anywhere.
        asm volatile("s_waitcnt vmcnt(0)" ::: "memory");
        __syncthreads();                 // all waves drained before the add
        if (threadIdx.x == 0) {
            __hip_atomic_fetch_add(cnt, 1u, __ATOMIC_RELAXED, __HIP_MEMORY_SCOPE_AGENT);
            const unsigned int target = (unsigned int)(t + 1) * SCAN_BLOCKS;
            while (__hip_atomic_load(cnt, __ATOMIC_RELAXED, __HIP_MEMORY_SCOPE_AGENT) < target) {
                __builtin_amdgcn_s_sleep(1);
            }
        }
        __syncthreads();
    }

#pragma unroll
    for (int i = 0; i < 4; i++) hf[(m0 + quad * 4 + i) * H + cj] = hprev[i];
}

extern "C" void kernel_launch(void* const* d_in, const int* in_sizes, int n_in,
                              void* d_out, int out_size, void* d_ws, size_t ws_size,
                              hipStream_t stream) {
    const int*   tokens = (const int*)d_in[0];
    const float* h0     = (const float*)d_in[1];
    const float* emb    = (const float*)d_in[2];
    const float* W_ih   = (const float*)d_in[3];
    const float* W_hh   = (const float*)d_in[4];
    const float* b_ih   = (const float*)d_in[5];
    const float* b_hh   = (const float*)d_in[6];
    float*       out    = (float*)d_out;

    // ws: [0,1MiB) h state + barrier | [1MiB,+6MiB) W_ih bf16 | +6MiB W_hh bf16 | xp chunk
    char* ws = (char*)d_ws;
    float* hf0 = (float*)ws;                                // 256 KiB (f32 h)
    unsigned short* hb0 = (unsigned short*)(ws + 524288);   // 128 KiB
    unsigned short* hb1 = hb0 + BB * H;                     // 128 KiB
    unsigned int* cnt = (unsigned int*)(ws + 786432);       // barrier counter
    unsigned short* Wib = (unsigned short*)(ws + 1048576);          // 6 MiB
    unsigned short* Whb = (unsigned short*)(ws + 1048576 + 6291456);// 6 MiB
    unsigned short* xp  = (unsigned short*)(ws + 13631488);

    const size_t slab = (size_t)BB * G3 * 2;                // 393,216 B per t
    long avail = (long)ws_size - 13631488L;
    if (avail < 0) avail = 0;
    long tc = (avail / (long)slab) & ~1L;                   // even
    if (tc < 2) tc = 2;
    if (tc > TT) tc = TT;
    const int Tc = (int)tc;

    hipLaunchKernelGGL(cvt_f32_bf16, dim3(G3 * H / 1024), dim3(256), 0, stream, W_ih, Wib);
    hipLaunchKernelGGL(cvt_f32_bf16, dim3(G3 * H / 1024), dim3(256), 0, stream, W_hh, Whb);
    hipLaunchKernelGGL(init_all, dim3((BB * H) / 256), dim3(256), 0, stream, h0, hf0, hb0, cnt);

    for (int c0 = 0; c0 < TT; c0 += Tc) {
        const int Tl = (TT - c0 < Tc) ? (TT - c0) : Tc;     // even
        hipLaunchKernelGGL(gemm_xp, dim3(G3 / 128, Tl * BB / 128), dim3(256), 0, stream,
                           emb, tokens, Wib, b_ih, xp, c0 * BB);
        hipLaunchKernelGGL(gru_scan, dim3(SCAN_BLOCKS), dim3(256), 0, stream,
                           hb0, hb1, hf0, Whb, b_hh, xp, out, cnt, c0, Tl);
    }
}

// Round 2
// 3643.833 us; speedup vs baseline: 1.3739x; 1.0621x over previous
//
#include <hip/hip_runtime.h>
#include <math.h>

#define H 1024
#define BB 64
#define TT 256
#define G3 3072
#define SCAN_BLOCKS 64

typedef __attribute__((ext_vector_type(8))) short bf16x8;
typedef __attribute__((ext_vector_type(4))) float f32x4;

__device__ __forceinline__ unsigned short f2bf(float f) {
    union { float f; unsigned int i; } v; v.f = f;
    unsigned int x = v.i;
    unsigned int r = (x + 0x7fffu + ((x >> 16) & 1u)) >> 16;   // RNE
    return (unsigned short)r;
}
__device__ __forceinline__ float bf2f(unsigned short u) {
    union { unsigned int i; float f; } v; v.i = ((unsigned int)u) << 16; return v.f;
}

// f32 -> bf16 bulk convert (for W_ih / W_hh), 4 elems/thread
__global__ void cvt_f32_bf16(const float* __restrict__ src,
                             unsigned short* __restrict__ dst) {
    int i = (blockIdx.x * 256 + threadIdx.x) * 4;
    float4 v = *(const float4*)(src + i);
    ushort4 o;
    o.x = f2bf(v.x); o.y = f2bf(v.y); o.z = f2bf(v.z); o.w = f2bf(v.w);
    *(ushort4*)(dst + i) = o;
}

// init: hf = h0 (f32), hb = bf16(h0), zero the grid-barrier counter
__global__ void init_all(const float* __restrict__ h0,
                         float* __restrict__ hf, unsigned short* __restrict__ hb,
                         unsigned int* __restrict__ cnt) {
    int i = blockIdx.x * 256 + threadIdx.x;
    if (i == 0) *cnt = 0u;             // kernel boundary orders this vs scan
    float v = h0[i];
    hf[i] = v;
    hb[i] = f2bf(v);
}

// load 8 consecutive f32, relu, convert to bf16x8
__device__ __forceinline__ bf16x8 load8_relu_bf(const float* p) {
    float4 u = *(const float4*)p;
    float4 v = *(const float4*)(p + 4);
    bf16x8 r;
    r[0] = (short)f2bf(fmaxf(u.x, 0.f));
    r[1] = (short)f2bf(fmaxf(u.y, 0.f));
    r[2] = (short)f2bf(fmaxf(u.z, 0.f));
    r[3] = (short)f2bf(fmaxf(u.w, 0.f));
    r[4] = (short)f2bf(fmaxf(v.x, 0.f));
    r[5] = (short)f2bf(fmaxf(v.y, 0.f));
    r[6] = (short)f2bf(fmaxf(v.z, 0.f));
    r[7] = (short)f2bf(fmaxf(v.w, 0.f));
    return r;
}

// ---- xp_chunk = relu(emb[tokens]) @ W_ih^T + b_ih -> bf16 [Tl*64, 3072] ----
// (unchanged from the passing round)
__global__ __launch_bounds__(256) void gemm_xp(
    const float* __restrict__ emb,
    const int* __restrict__ tokens,
    const unsigned short* __restrict__ Wb,
    const float* __restrict__ b_ih,
    unsigned short* __restrict__ xp,
    int row0)
{
    const int tileN = blockIdx.x * 128;
    const int tileM = blockIdx.y * 128;
    const int wave  = threadIdx.x >> 6;
    const int lane  = threadIdx.x & 63;
    const int row   = lane & 15;
    const int quad  = lane >> 4;
    const int mb = tileM + (wave >> 1) * 64;
    const int nb = tileN + (wave & 1) * 64;

    const float* arow[4];
#pragma unroll
    for (int i = 0; i < 4; i++) {
        int tok = tokens[row0 + mb + row + i * 16];
        arow[i] = emb + (size_t)tok * H + quad * 8;
    }
    const unsigned short* bptr = Wb + (size_t)(nb + row) * H + quad * 8;

    f32x4 acc[4][4] = {};
    for (int k = 0; k < H; k += 32) {
        bf16x8 a[4], b[4];
#pragma unroll
        for (int i = 0; i < 4; i++) a[i] = load8_relu_bf(arow[i] + k);
#pragma unroll
        for (int j = 0; j < 4; j++) b[j] = *(const bf16x8*)(bptr + (size_t)j * 16 * H + k);
#pragma unroll
        for (int i = 0; i < 4; i++)
#pragma unroll
            for (int j = 0; j < 4; j++)
                acc[i][j] = __builtin_amdgcn_mfma_f32_16x16x32_bf16(a[i], b[j], acc[i][j], 0, 0, 0);
    }

#pragma unroll
    for (int i = 0; i < 4; i++) {
        int m = mb + i * 16 + quad * 4;
#pragma unroll
        for (int j = 0; j < 4; j++) {
            int n = nb + j * 16 + row;
            float bias = b_ih[n];
#pragma unroll
            for (int rg = 0; rg < 4; rg++) {
                xp[(size_t)(m + rg) * G3 + n] = f2bf(acc[i][j][rg] + bias);
            }
        }
    }
}

// ---- persistent GRU scan ----
// This round's changes (latency model: 12.3 us/step was dominated by the
// per-iteration sc1 h-load -> MFMA dependent chain + 384 KB/step of W_hh
// L1 re-reads):
//  1. h prefetch: all 32 16B fragments loaded into registers up-front
//     (fully unrolled, static indices -> VGPRs). L3 latency paid once.
//  2. W_hh gates r,z staged in LDS once per dispatch, PRE-PERMUTED into
//     fragment order [gate][kk][lane]x16B so the per-step reads are linear
//     ds_read_b128 with immediate offsets (conflict-free, no addr VALU).
//     Gate n stays on the L1 path (64 KB static-LDS limit), so LDS and L1
//     serve W in parallel.
// Barrier stays fence-free (relaxed agent atomics; h via sc1 write-through).
__global__ __launch_bounds__(256) void gru_scan(
    unsigned short* __restrict__ hb0,          // bf16 h ping [64*1024]
    unsigned short* __restrict__ hb1,          // bf16 h pong
    float* __restrict__ hf,                    // f32 h (chunk handoff)
    const unsigned short* __restrict__ Whb,    // [3072,1024] bf16
    const float* __restrict__ b_hh,            // [3072] f32
    const unsigned short* __restrict__ xp,     // chunk base, [Tl*64, 3072] bf16
    float* __restrict__ out,                   // [B,T,H] f32
    unsigned int* __restrict__ cnt,            // grid-barrier counter
    int t0, int Tl)
{
    const int j0   = blockIdx.x * 16;
    const int wave = threadIdx.x >> 6;
    const int lane = threadIdx.x & 63;
    const int row  = lane & 15;
    const int quad = lane >> 4;
    const int m0   = wave * 16;
    const int cj   = j0 + row;

    // ---- stage W gates 0 (r) and 1 (z) into LDS in fragment order ----
    // fragment (g, kk, l) = W[g*H + j0 + (l&15)][ (l>>4)*8 + kk*32 .. +8 ]
    // stored at Wlds + (g*2048 + kk*64 + l)*8 shorts. Per-step read for
    // lane l, k-iter kk is then a linear ds_read_b128 at an imm offset.
    __shared__ unsigned short Wlds[2 * 32 * 64 * 8];   // 64 KiB
#pragma unroll
    for (int it = 0; it < 16; it++) {
        int idx = it * 256 + threadIdx.x;              // 0..4095
        int g   = idx >> 11;
        int rem = idx & 2047;
        int kk  = rem >> 6;
        int l   = rem & 63;
        int r   = l & 15;
        int q   = l >> 4;
        const unsigned short* src = Whb + (size_t)(g * H + j0 + r) * H + q * 8 + kk * 32;
        *(bf16x8*)(Wlds + (size_t)idx * 8) = *(const bf16x8*)src;
    }
    __syncthreads();
    const unsigned short* wl = Wlds + lane * 8;

    const float bhr = b_hh[cj];
    const float bhz = b_hh[H + cj];
    const float bhn = b_hh[2 * H + cj];

    // gate n (2) stays on the global/L1 path
    const unsigned short* w2 = Whb + (size_t)(2 * H + j0 + row) * H + quad * 8;

    float hprev[4];
#pragma unroll
    for (int i = 0; i < 4; i++) hprev[i] = hf[(m0 + quad * 4 + i) * H + cj];

    for (int s = 0; s < Tl; s++) {
        const int t = t0 + s;
        const unsigned short* hin  = (t & 1) ? hb1 : hb0;
        unsigned short*       hout = (t & 1) ? hb0 : hb1;

        // ---- bulk h prefetch: 32 x 16B sc1 fragments into registers ----
        const unsigned short* aptr = hin + (size_t)(m0 + row) * H + quad * 8;
        unsigned long long hu0[32], hu1[32];
#pragma unroll
        for (int kk = 0; kk < 32; kk++) {
            hu0[kk] = __hip_atomic_load((const unsigned long long*)(aptr + kk * 32),
                                        __ATOMIC_RELAXED, __HIP_MEMORY_SCOPE_AGENT);
            hu1[kk] = __hip_atomic_load((const unsigned long long*)(aptr + kk * 32 + 4),
                                        __ATOMIC_RELAXED, __HIP_MEMORY_SCOPE_AGENT);
        }

        // xp loads (needed only in the epilogue; independent of h)
        float xr[4], xz[4], xn[4];
#pragma unroll
        for (int i = 0; i < 4; i++) {
            int b = m0 + quad * 4 + i;
            const unsigned short* xpb = xp + ((size_t)s * BB + b) * G3;
            xr[i] = bf2f(xpb[cj]);
            xz[i] = bf2f(xpb[H + cj]);
            xn[i] = bf2f(xpb[2 * H + cj]);
        }

        f32x4 acc0 = {}, acc1 = {}, acc2 = {};
#pragma unroll
        for (int kk = 0; kk < 32; kk++) {
            union { bf16x8 v; unsigned long long u[2]; } a;
            a.u[0] = hu0[kk];
            a.u[1] = hu1[kk];
            bf16x8 f0 = *(const bf16x8*)(wl + kk * 512);            // LDS gate r
            bf16x8 f1 = *(const bf16x8*)(wl + 16384 + kk * 512);    // LDS gate z
            bf16x8 f2 = *(const bf16x8*)(w2 + kk * 32);             // L1  gate n
            acc0 = __builtin_amdgcn_mfma_f32_16x16x32_bf16(a.v, f0, acc0, 0, 0, 0);
            acc1 = __builtin_amdgcn_mfma_f32_16x16x32_bf16(a.v, f1, acc1, 0, 0, 0);
            acc2 = __builtin_amdgcn_mfma_f32_16x16x32_bf16(a.v, f2, acc2, 0, 0, 0);
        }

#pragma unroll
        for (int i = 0; i < 4; i++) {
            int b = m0 + quad * 4 + i;
            float hr = acc0[i] + bhr;
            float hz = acc1[i] + bhz;
            float hn = acc2[i] + bhn;
            float r = 1.f / (1.f + __expf(-(xr[i] + hr)));
            float z = 1.f / (1.f + __expf(-(xz[i] + hz)));
            float targ = xn[i] + r * hn;
            targ = fminf(fmaxf(targ, -30.f), 30.f);
            float n = tanhf(targ);
            float hnew = (1.f - z) * n + z * hprev[i];
            hnew = fminf(fmaxf(hnew, -4.f), 4.f);   // invisible when correct
            hprev[i] = hnew;

            // h store: pair adjacent columns (lanes r, r^1) into one 4B
            // write-through agent-scope atomic store.
            unsigned int mybf = (unsigned int)f2bf(hnew);
            unsigned int pbf  = (unsigned int)__shfl_xor((int)mybf, 1);
            if (!(row & 1)) {
                unsigned int word = (mybf & 0xffffu) | (pbf << 16);
                __hip_atomic_store((unsigned int*)(hout + (size_t)b * H + (cj & ~1)),
                                   word, __ATOMIC_RELAXED, __HIP_MEMORY_SCOPE_AGENT);
            }
            out[((size_t)b * TT + t) * H + cj] = hnew;   // normal store; kernel-end flush
        }

        // ---- grid barrier (fence-free) ----
        asm volatile("s_waitcnt vmcnt(0)" ::: "memory");
        __syncthreads();                 // all waves drained before the add
        if (threadIdx.x == 0) {
            __hip_atomic_fetch_add(cnt, 1u, __ATOMIC_RELAXED, __HIP_MEMORY_SCOPE_AGENT);
            const unsigned int target = (unsigned int)(t + 1) * SCAN_BLOCKS;
            while (__hip_atomic_load(cnt, __ATOMIC_RELAXED, __HIP_MEMORY_SCOPE_AGENT) < target) {
                __builtin_amdgcn_s_sleep(1);
            }
        }
        __syncthreads();
    }

#pragma unroll
    for (int i = 0; i < 4; i++) hf[(m0 + quad * 4 + i) * H + cj] = hprev[i];
}

extern "C" void kernel_launch(void* const* d_in, const int* in_sizes, int n_in,
                              void* d_out, int out_size, void* d_ws, size_t ws_size,
                              hipStream_t stream) {
    const int*   tokens = (const int*)d_in[0];
    const float* h0     = (const float*)d_in[1];
    const float* emb    = (const float*)d_in[2];
    const float* W_ih   = (const float*)d_in[3];
    const float* W_hh   = (const float*)d_in[4];
    const float* b_ih   = (const float*)d_in[5];
    const float* b_hh   = (const float*)d_in[6];
    float*       out    = (float*)d_out;

    // ws: [0,1MiB) h state + barrier | [1MiB,+6MiB) W_ih bf16 | +6MiB W_hh bf16 | xp chunk
    char* ws = (char*)d_ws;
    float* hf0 = (float*)ws;                                // 256 KiB (f32 h)
    unsigned short* hb0 = (unsigned short*)(ws + 524288);   // 128 KiB
    unsigned short* hb1 = hb0 + BB * H;                     // 128 KiB
    unsigned int* cnt = (unsigned int*)(ws + 786432);       // barrier counter
    unsigned short* Wib = (unsigned short*)(ws + 1048576);          // 6 MiB
    unsigned short* Whb = (unsigned short*)(ws + 1048576 + 6291456);// 6 MiB
    unsigned short* xp  = (unsigned short*)(ws + 13631488);

    const size_t slab = (size_t)BB * G3 * 2;                // 393,216 B per t
    long avail = (long)ws_size - 13631488L;
    if (avail < 0) avail = 0;
    long tc = (avail / (long)slab) & ~1L;                   // even
    if (tc < 2) tc = 2;
    if (tc > TT) tc = TT;
    const int Tc = (int)tc;

    hipLaunchKernelGGL(cvt_f32_bf16, dim3(G3 * H / 1024), dim3(256), 0, stream, W_ih, Wib);
    hipLaunchKernelGGL(cvt_f32_bf16, dim3(G3 * H / 1024), dim3(256), 0, stream, W_hh, Whb);
    hipLaunchKernelGGL(init_all, dim3((BB * H) / 256), dim3(256), 0, stream, h0, hf0, hb0, cnt);

    for (int c0 = 0; c0 < TT; c0 += Tc) {
        const int Tl = (TT - c0 < Tc) ? (TT - c0) : Tc;     // even
        hipLaunchKernelGGL(gemm_xp, dim3(G3 / 128, Tl * BB / 128), dim3(256), 0, stream,
                           emb, tokens, Wib, b_ih, xp, c0 * BB);
        hipLaunchKernelGGL(gru_scan, dim3(SCAN_BLOCKS), dim3(256), 0, stream,
                           hb0, hb1, hf0, Whb, b_hh, xp, out, cnt, c0, Tl);
    }
}

// Round 3
// 3590.039 us; speedup vs baseline: 1.3944x; 1.0150x over previous
//
#include <hip/hip_runtime.h>
#include <math.h>

#define H 1024
#define BB 64
#define TT 256
#define G3 3072
#define SCAN_BLOCKS 64          // 4 groups x 16 blocks
#define GROUPS 4
#define BPG 16                  // blocks per group (barrier participants)

typedef __attribute__((ext_vector_type(8))) short bf16x8;
typedef __attribute__((ext_vector_type(4))) float f32x4;

__device__ __forceinline__ unsigned short f2bf(float f) {
    union { float f; unsigned int i; } v; v.f = f;
    unsigned int x = v.i;
    unsigned int r = (x + 0x7fffu + ((x >> 16) & 1u)) >> 16;   // RNE
    return (unsigned short)r;
}
__device__ __forceinline__ float bf2f(unsigned short u) {
    union { unsigned int i; float f; } v; v.i = ((unsigned int)u) << 16; return v.f;
}

// f32 -> bf16 bulk convert (for W_ih), 4 elems/thread
__global__ void cvt_f32_bf16(const float* __restrict__ src,
                             unsigned short* __restrict__ dst) {
    int i = (blockIdx.x * 256 + threadIdx.x) * 4;
    float4 v = *(const float4*)(src + i);
    ushort4 o;
    o.x = f2bf(v.x); o.y = f2bf(v.y); o.z = f2bf(v.z); o.w = f2bf(v.w);
    *(ushort4*)(dst + i) = o;
}

// W_hh -> bf16 in MFMA-fragment order:
// frag idx = ((tau*3 + gate)*32 + kk)*64 + lane, each frag = 8 shorts (16B).
// frag(tau,gate,kk,l) = W[gate*H + tau*16 + (l&15)][(l>>4)*8 + kk*32 .. +8]
// Per k-iter a wave then reads one CONTIGUOUS 1KB line per gate.
__global__ void cvt_whh_perm(const float* __restrict__ src,
                             unsigned short* __restrict__ dst) {
    int idx = blockIdx.x * 256 + threadIdx.x;      // 0 .. 393215
    int tau = idx / 6144;
    int rem = idx % 6144;
    int gate = rem / 2048;
    int r2  = rem % 2048;
    int kk  = r2 >> 6;
    int l   = r2 & 63;
    int srow = gate * H + tau * 16 + (l & 15);
    int scol = (l >> 4) * 8 + kk * 32;
    const float* s = src + (size_t)srow * H + scol;
    float4 u = *(const float4*)s;
    float4 v = *(const float4*)(s + 4);
    unsigned short* d = dst + (size_t)idx * 8;
    d[0] = f2bf(u.x); d[1] = f2bf(u.y); d[2] = f2bf(u.z); d[3] = f2bf(u.w);
    d[4] = f2bf(v.x); d[5] = f2bf(v.y); d[6] = f2bf(v.z); d[7] = f2bf(v.w);
}

// init: hf = h0 (f32), hb = bf16(h0), zero the 4 per-group barrier counters
__global__ void init_all(const float* __restrict__ h0,
                         float* __restrict__ hf, unsigned short* __restrict__ hb,
                         unsigned int* __restrict__ cnt) {
    int i = blockIdx.x * 256 + threadIdx.x;
    if (i < GROUPS) cnt[i * 64] = 0u;  // 256B-spaced counters; ordered by kernel boundary
    float v = h0[i];
    hf[i] = v;
    hb[i] = f2bf(v);
}

// load 8 consecutive f32, relu, convert to bf16x8
__device__ __forceinline__ bf16x8 load8_relu_bf(const float* p) {
    float4 u = *(const float4*)p;
    float4 v = *(const float4*)(p + 4);
    bf16x8 r;
    r[0] = (short)f2bf(fmaxf(u.x, 0.f));
    r[1] = (short)f2bf(fmaxf(u.y, 0.f));
    r[2] = (short)f2bf(fmaxf(u.z, 0.f));
    r[3] = (short)f2bf(fmaxf(u.w, 0.f));
    r[4] = (short)f2bf(fmaxf(v.x, 0.f));
    r[5] = (short)f2bf(fmaxf(v.y, 0.f));
    r[6] = (short)f2bf(fmaxf(v.z, 0.f));
    r[7] = (short)f2bf(fmaxf(v.w, 0.f));
    return r;
}

// ---- xp_chunk = relu(emb[tokens]) @ W_ih^T + b_ih -> bf16 [Tl*64, 3072] ----
// (unchanged from the passing round)
__global__ __launch_bounds__(256) void gemm_xp(
    const float* __restrict__ emb,
    const int* __restrict__ tokens,
    const unsigned short* __restrict__ Wb,
    const float* __restrict__ b_ih,
    unsigned short* __restrict__ xp,
    int row0)
{
    const int tileN = blockIdx.x * 128;
    const int tileM = blockIdx.y * 128;
    const int wave  = threadIdx.x >> 6;
    const int lane  = threadIdx.x & 63;
    const int row   = lane & 15;
    const int quad  = lane >> 4;
    const int mb = tileM + (wave >> 1) * 64;
    const int nb = tileN + (wave & 1) * 64;

    const float* arow[4];
#pragma unroll
    for (int i = 0; i < 4; i++) {
        int tok = tokens[row0 + mb + row + i * 16];
        arow[i] = emb + (size_t)tok * H + quad * 8;
    }
    const unsigned short* bptr = Wb + (size_t)(nb + row) * H + quad * 8;

    f32x4 acc[4][4] = {};
    for (int k = 0; k < H; k += 32) {
        bf16x8 a[4], b[4];
#pragma unroll
        for (int i = 0; i < 4; i++) a[i] = load8_relu_bf(arow[i] + k);
#pragma unroll
        for (int j = 0; j < 4; j++) b[j] = *(const bf16x8*)(bptr + (size_t)j * 16 * H + k);
#pragma unroll
        for (int i = 0; i < 4; i++)
#pragma unroll
            for (int j = 0; j < 4; j++)
                acc[i][j] = __builtin_amdgcn_mfma_f32_16x16x32_bf16(a[i], b[j], acc[i][j], 0, 0, 0);
    }

#pragma unroll
    for (int i = 0; i < 4; i++) {
        int m = mb + i * 16 + quad * 4;
#pragma unroll
        for (int j = 0; j < 4; j++) {
            int n = nb + j * 16 + row;
            float bias = b_ih[n];
#pragma unroll
            for (int rg = 0; rg < 4; rg++) {
                xp[(size_t)(m + rg) * G3 + n] = f2bf(acc[i][j][rg] + bias);
            }
        }
    }
}

// ---- persistent GRU scan, GROUP-DECOUPLED ----
// Batch rows are independent: group g (blocks 16g..16g+15) owns batch rows
// [16g,16g+16) and syncs ONLY within itself on its own 256B-spaced counter.
// 4 independent barriers of 16 arrivals (vs 1 of 64): less line contention,
// fewer serialized atomic adds, and straggler skew no longer couples the
// whole grid. Block kb in a group owns h-cols [64kb,64kb+64); wave w owns
// 16 cols. Per-step critical path trims: `out` stores moved AFTER the
// barrier-arrive (overlap with wait); per-wave lane0 poll (no post-poll
// __syncthreads). W_hh read from the fragment-permuted Wp buffer: one
// contiguous 1KB wave-read per gate per k-iter (L2-streaming friendly).
__global__ __launch_bounds__(256, 1) void gru_scan(
    unsigned short* __restrict__ hb0,          // bf16 h ping [64*1024]
    unsigned short* __restrict__ hb1,          // bf16 h pong
    float* __restrict__ hf,                    // f32 h (chunk handoff)
    const unsigned short* __restrict__ Wp,     // permuted W_hh bf16 (see cvt_whh_perm)
    const float* __restrict__ b_hh,            // [3072] f32
    const unsigned short* __restrict__ xp,     // chunk base, [Tl*64, 3072] bf16
    float* __restrict__ out,                   // [B,T,H] f32
    unsigned int* __restrict__ cnt,            // 4 barrier counters, 256B apart
    int t0, int Tl)
{
    const int g    = blockIdx.x >> 4;          // group = batch-row slice
    const int kb   = blockIdx.x & 15;          // block-in-group = col slice
    const int wave = threadIdx.x >> 6;
    const int lane = threadIdx.x & 63;
    const int row  = lane & 15;
    const int quad = lane >> 4;
    const int r0   = g * 16;                   // group's batch rows
    const int c0   = kb * 64 + wave * 16;      // wave's h-cols
    const int cj   = c0 + row;
    unsigned int* cg = cnt + g * 64;           // group counter (256B spacing)

    const float bhr = b_hh[cj];
    const float bhz = b_hh[H + cj];
    const float bhn = b_hh[2 * H + cj];

    // wave's W fragments: tile tau = c0/16; 3 gates at +0 / +16384 / +32768 shorts
    const int tauw = (c0 >> 4);
    const unsigned short* wl = Wp + (size_t)tauw * 49152 + (size_t)lane * 8;

    float hprev[4];
#pragma unroll
    for (int i = 0; i < 4; i++) hprev[i] = hf[(r0 + quad * 4 + i) * H + cj];

    for (int s = 0; s < Tl; s++) {
        const int t = t0 + s;
        const unsigned short* hin  = (t & 1) ? hb1 : hb0;
        unsigned short*       hout = (t & 1) ? hb0 : hb1;

        // ---- bulk h prefetch: group's 16 rows, 32 x 16B sc1 fragments ----
        const unsigned short* aptr = hin + (size_t)(r0 + row) * H + quad * 8;
        unsigned long long hu0[32], hu1[32];
#pragma unroll
        for (int kk = 0; kk < 32; kk++) {
            hu0[kk] = __hip_atomic_load((const unsigned long long*)(aptr + kk * 32),
                                        __ATOMIC_RELAXED, __HIP_MEMORY_SCOPE_AGENT);
            hu1[kk] = __hip_atomic_load((const unsigned long long*)(aptr + kk * 32 + 4),
                                        __ATOMIC_RELAXED, __HIP_MEMORY_SCOPE_AGENT);
        }

        // xp loads (epilogue-only; independent of h)
        float xr[4], xz[4], xn[4];
#pragma unroll
        for (int i = 0; i < 4; i++) {
            int b = r0 + quad * 4 + i;
            const unsigned short* xpb = xp + ((size_t)s * BB + b) * G3;
            xr[i] = bf2f(xpb[cj]);
            xz[i] = bf2f(xpb[H + cj]);
            xn[i] = bf2f(xpb[2 * H + cj]);
        }

        f32x4 acc0 = {}, acc1 = {}, acc2 = {};
#pragma unroll
        for (int kk = 0; kk < 32; kk++) {
            union { bf16x8 v; unsigned long long u[2]; } a;
            a.u[0] = hu0[kk];
            a.u[1] = hu1[kk];
            bf16x8 f0 = *(const bf16x8*)(wl + kk * 512);            // gate r
            bf16x8 f1 = *(const bf16x8*)(wl + 16384 + kk * 512);    // gate z
            bf16x8 f2 = *(const bf16x8*)(wl + 32768 + kk * 512);    // gate n
            acc0 = __builtin_amdgcn_mfma_f32_16x16x32_bf16(a.v, f0, acc0, 0, 0, 0);
            acc1 = __builtin_amdgcn_mfma_f32_16x16x32_bf16(a.v, f1, acc1, 0, 0, 0);
            acc2 = __builtin_amdgcn_mfma_f32_16x16x32_bf16(a.v, f2, acc2, 0, 0, 0);
        }

        float hnew[4];
#pragma unroll
        for (int i = 0; i < 4; i++) {
            int b = r0 + quad * 4 + i;
            float hr = acc0[i] + bhr;
            float hz = acc1[i] + bhz;
            float hn = acc2[i] + bhn;
            float r = 1.f / (1.f + __expf(-(xr[i] + hr)));
            float z = 1.f / (1.f + __expf(-(xz[i] + hz)));
            float targ = xn[i] + r * hn;
            targ = fminf(fmaxf(targ, -30.f), 30.f);
            float n = tanhf(targ);
            float hv = (1.f - z) * n + z * hprev[i];
            hv = fminf(fmaxf(hv, -4.f), 4.f);   // invisible when correct
            hprev[i] = hv;
            hnew[i] = hv;

            // h store: pair adjacent cols (lanes l, l^1) into one 4B
            // write-through agent-scope atomic store.
            unsigned int mybf = (unsigned int)f2bf(hv);
            unsigned int pbf  = (unsigned int)__shfl_xor((int)mybf, 1);
            if (!(row & 1)) {
                unsigned int word = (mybf & 0xffffu) | (pbf << 16);
                __hip_atomic_store((unsigned int*)(hout + (size_t)b * H + (cj & ~1)),
                                   word, __ATOMIC_RELAXED, __HIP_MEMORY_SCOPE_AGENT);
            }
        }

        // ---- group barrier: arrive early, overlap out-stores with wait ----
        asm volatile("s_waitcnt vmcnt(0)" ::: "memory");   // h stores acked at L3
        __syncthreads();                                   // all 4 waves drained
        if (threadIdx.x == 0)
            __hip_atomic_fetch_add(cg, 1u, __ATOMIC_RELAXED, __HIP_MEMORY_SCOPE_AGENT);

        // out stores (normal, write-back) overlap with the barrier wait
#pragma unroll
        for (int i = 0; i < 4; i++) {
            int b = r0 + quad * 4 + i;
            out[((size_t)b * TT + t) * H + cj] = hnew[i];
        }

        // per-wave poll: wave proceeds as soon as its group is done
        if (lane == 0) {
            const unsigned int target = (unsigned int)(t + 1) * BPG;
            while (__hip_atomic_load(cg, __ATOMIC_RELAXED, __HIP_MEMORY_SCOPE_AGENT) < target) {
                __builtin_amdgcn_s_sleep(1);
            }
        }
        asm volatile("" ::: "memory");   // no hoisting of next-step h loads above poll
    }

#pragma unroll
    for (int i = 0; i < 4; i++) hf[(r0 + quad * 4 + i) * H + cj] = hprev[i];
}

extern "C" void kernel_launch(void* const* d_in, const int* in_sizes, int n_in,
                              void* d_out, int out_size, void* d_ws, size_t ws_size,
                              hipStream_t stream) {
    const int*   tokens = (const int*)d_in[0];
    const float* h0     = (const float*)d_in[1];
    const float* emb    = (const float*)d_in[2];
    const float* W_ih   = (const float*)d_in[3];
    const float* W_hh   = (const float*)d_in[4];
    const float* b_ih   = (const float*)d_in[5];
    const float* b_hh   = (const float*)d_in[6];
    float*       out    = (float*)d_out;

    // ws: [0,1MiB) h state + barriers | [1MiB,+6MiB) W_ih bf16 | +6MiB W_hh perm bf16 | xp chunk
    char* ws = (char*)d_ws;
    float* hf0 = (float*)ws;                                // 256 KiB (f32 h)
    unsigned short* hb0 = (unsigned short*)(ws + 524288);   // 128 KiB
    unsigned short* hb1 = hb0 + BB * H;                     // 128 KiB
    unsigned int* cnt = (unsigned int*)(ws + 786432);       // 4 counters, 256B apart
    unsigned short* Wib = (unsigned short*)(ws + 1048576);          // 6 MiB
    unsigned short* Wpb = (unsigned short*)(ws + 1048576 + 6291456);// 6 MiB (permuted)
    unsigned short* xp  = (unsigned short*)(ws + 13631488);

    const size_t slab = (size_t)BB * G3 * 2;                // 393,216 B per t
    long avail = (long)ws_size - 13631488L;
    if (avail < 0) avail = 0;
    long tc = (avail / (long)slab) & ~1L;                   // even
    if (tc < 2) tc = 2;
    if (tc > TT) tc = TT;
    const int Tc = (int)tc;

    hipLaunchKernelGGL(cvt_f32_bf16, dim3(G3 * H / 1024), dim3(256), 0, stream, W_ih, Wib);
    hipLaunchKernelGGL(cvt_whh_perm, dim3(1536), dim3(256), 0, stream, W_hh, Wpb);
    hipLaunchKernelGGL(init_all, dim3((BB * H) / 256), dim3(256), 0, stream, h0, hf0, hb0, cnt);

    for (int c0 = 0; c0 < TT; c0 += Tc) {
        const int Tl = (TT - c0 < Tc) ? (TT - c0) : Tc;     // even
        hipLaunchKernelGGL(gemm_xp, dim3(G3 / 128, Tl * BB / 128), dim3(256), 0, stream,
                           emb, tokens, Wib, b_ih, xp, c0 * BB);
        hipLaunchKernelGGL(gru_scan, dim3(SCAN_BLOCKS), dim3(256), 0, stream,
                           hb0, hb1, hf0, Wpb, b_hh, xp, out, cnt, c0, Tl);
    }
}